// Round 1
// baseline (1858.579 us; speedup 1.0000x reference)
//
#include <hip/hip_runtime.h>
#include <math.h>

// Problem constants (from reference)
#define BG    100        // graphs
#define NPG   500        // nodes per graph (layer 1)
#define FD    128        // feature dim (F_IN == H == 128)
#define EE    600000     // edges
#define NN    50000      // total nodes layer 1
#define K1    250
#define K2    125
#define K3    63

// ---------------- scatter (segment-sum of messages) ----------------
// 32 threads per edge, float4 per thread -> 128 dims.
__global__ void scatter_first_kernel(const int* __restrict__ ei, const float* __restrict__ x,
                                     float* __restrict__ agg, float* __restrict__ cnt, int E) {
    long long t = (long long)blockIdx.x * blockDim.x + threadIdx.x;
    int e = (int)(t >> 5);
    if (e >= E) return;
    int c = (int)(t & 31);
    int s = ei[e], d = ei[E + e];
    float4 v = ((const float4*)(x + (long long)s * FD))[c];
    float* a = agg + (long long)d * FD + c * 4;
    atomicAdd(a + 0, v.x); atomicAdd(a + 1, v.y);
    atomicAdd(a + 2, v.z); atomicAdd(a + 3, v.w);
    if (c == 0) atomicAdd(cnt + d, 1.0f);
}

__global__ void scatter_masked_kernel(const int* __restrict__ src, const int* __restrict__ dst,
                                      const float* __restrict__ em, const float* __restrict__ x,
                                      float* __restrict__ agg, float* __restrict__ cnt, int E) {
    long long t = (long long)blockIdx.x * blockDim.x + threadIdx.x;
    int e = (int)(t >> 5);
    if (e >= E) return;
    if (em[e] == 0.0f) return;                 // dead edge: contributes 0 in reference
    int c = (int)(t & 31);
    int s = src[e], d = dst[e];
    float4 v = ((const float4*)(x + (long long)s * FD))[c];
    float* a = agg + (long long)d * FD + c * 4;
    atomicAdd(a + 0, v.x); atomicAdd(a + 1, v.y);
    atomicAdd(a + 2, v.z); atomicAdd(a + 3, v.w);
    if (c == 0) atomicAdd(cnt + d, 1.0f);
}

__global__ void cntinv_kernel(float* __restrict__ cnt, int n) {
    int i = blockIdx.x * blockDim.x + threadIdx.x;
    if (i < n) cnt[i] = 1.0f / fmaxf(cnt[i], 1.0f);
}

// ---------------- fused SAGE GEMM: relu(mean@Wl + x@Wr + bl) ----------------
// Tile: 64 rows x 128 cols, K=256 logical (mean | x), k-tile 32.
// Thread micro-tile 4 rows x 8 cols (256 threads).
__global__ __launch_bounds__(256) void sage_gemm_kernel(
        const float* __restrict__ agg, const float* __restrict__ cinv,
        const float* __restrict__ x,
        const float* __restrict__ Wl, const float* __restrict__ Wr,
        const float* __restrict__ bl, float* __restrict__ hout, int M) {
    __shared__ float As[32 * 64];    // [kk][row]
    __shared__ float Ws[32 * 128];   // [kk][col]
    int tid  = threadIdx.x;
    int row0 = blockIdx.x * 64;
    int tr   = tid >> 4;             // 0..15 -> rows 4*tr..4*tr+3
    int tc   = tid & 15;             // 0..15 -> cols 8*tc..8*tc+7
    float acc[4][8];
#pragma unroll
    for (int r = 0; r < 4; r++)
#pragma unroll
        for (int c = 0; c < 8; c++) acc[r][c] = 0.0f;

    int lrow = tid >> 3;             // 0..31
    int lk   = (tid & 7) * 4;        // 0,4,..,28

    for (int kt = 0; kt < 8; ++kt) {
        bool isMean = kt < 4;
        int kcol = (isMean ? kt * 32 : (kt - 4) * 32) + lk;
        const float* Ab = isMean ? agg : x;
#pragma unroll
        for (int p = 0; p < 2; ++p) {
            int row  = p * 32 + lrow;
            int grow = row0 + row; if (grow > M - 1) grow = M - 1;
            float4 v = *(const float4*)(Ab + (long long)grow * FD + kcol);
            if (isMean) { float s = cinv[grow]; v.x *= s; v.y *= s; v.z *= s; v.w *= s; }
            As[(lk + 0) * 64 + row] = v.x;
            As[(lk + 1) * 64 + row] = v.y;
            As[(lk + 2) * 64 + row] = v.z;
            As[(lk + 3) * 64 + row] = v.w;
        }
        {
            int wc  = (tid & 31) * 4;
            int wk0 = tid >> 5;                           // 0..7
            const float* WB = isMean ? Wl : Wr;
            int krow0 = isMean ? kt * 32 : (kt - 4) * 32;
#pragma unroll
            for (int q = 0; q < 4; ++q) {
                int kk = wk0 + q * 8;
                float4 v = *(const float4*)(WB + (long long)(krow0 + kk) * FD + wc);
                *(float4*)&Ws[kk * 128 + wc] = v;
            }
        }
        __syncthreads();
#pragma unroll
        for (int kk = 0; kk < 32; ++kk) {
            float4 a  = *(const float4*)&As[kk * 64 + tr * 4];
            float4 b0 = *(const float4*)&Ws[kk * 128 + tc * 8];
            float4 b1 = *(const float4*)&Ws[kk * 128 + tc * 8 + 4];
            float av[4] = {a.x, a.y, a.z, a.w};
            float bv[8] = {b0.x, b0.y, b0.z, b0.w, b1.x, b1.y, b1.z, b1.w};
#pragma unroll
            for (int r = 0; r < 4; r++)
#pragma unroll
                for (int c = 0; c < 8; c++) acc[r][c] += av[r] * bv[c];
        }
        __syncthreads();
    }
    float bvec[8];
#pragma unroll
    for (int c = 0; c < 8; c++) bvec[c] = bl[tc * 8 + c];
#pragma unroll
    for (int r = 0; r < 4; r++) {
        int grow = row0 + tr * 4 + r;
        if (grow < M) {
            float* dstp = hout + (long long)grow * FD + tc * 8;
#pragma unroll
            for (int c = 0; c < 8; c++) dstp[c] = fmaxf(acc[r][c] + bvec[c], 0.0f);
        }
    }
}

// ---------------- score = tanh(h.w / ||w||), one wave per node ----------------
__global__ void score_kernel(const float* __restrict__ h, const float* __restrict__ w,
                             float* __restrict__ score, int n) {
    int g = blockIdx.x * blockDim.x + threadIdx.x;
    int node = g >> 6, lane = g & 63;
    if (node >= n) return;
    float2 wv = ((const float2*)w)[lane];
    float2 xv = ((const float2*)(h + (long long)node * FD))[lane];
    float dot = xv.x * wv.x + xv.y * wv.y;
    float nrm = wv.x * wv.x + wv.y * wv.y;
    for (int off = 32; off; off >>= 1) {
        dot += __shfl_down(dot, off);
        nrm += __shfl_down(nrm, off);
    }
    if (lane == 0) score[node] = tanhf(dot / sqrtf(nrm));
}

// ---------------- per-graph top-k (bitonic sort in LDS, jax.lax.top_k order) ----------------
__global__ __launch_bounds__(256) void topk_kernel(const float* __restrict__ score,
        int n_per, int k, int SN, int* __restrict__ perm, float* __restrict__ topv,
        int* __restrict__ mapping) {
    __shared__ float skey[512];
    __shared__ int   sidx[512];
    int b = blockIdx.x, tid = threadIdx.x;
    for (int i = tid; i < SN; i += 256) {
        if (i < n_per) { skey[i] = score[b * n_per + i]; sidx[i] = i; }
        else           { skey[i] = -INFINITY;            sidx[i] = 0x7fffffff; }
    }
    __syncthreads();
    for (int ks = 2; ks <= SN; ks <<= 1) {
        for (int j = ks >> 1; j > 0; j >>= 1) {
            for (int i = tid; i < SN; i += 256) {
                int l = i ^ j;
                if (l > i) {
                    float ki = skey[i], kl = skey[l];
                    int   ii = sidx[i], il = sidx[l];
                    // "before" = higher score first; tie -> lower index first (jax.lax.top_k)
                    bool before = (ki > kl) || (ki == kl && ii < il);
                    bool up = ((i & ks) == 0);
                    if (up ? !before : before) {
                        skey[i] = kl; skey[l] = ki;
                        sidx[i] = il; sidx[l] = ii;
                    }
                }
            }
            __syncthreads();
        }
    }
    for (int i = tid; i < k; i += 256) {
        int old  = sidx[i];
        int oldg = b * n_per + old;
        int newg = b * k + i;
        perm[newg] = oldg;
        topv[newg] = skey[i];
        mapping[oldg] = newg;
    }
}

// ---------------- gather + scale: x_new = h[perm] * topv ----------------
__global__ void gather_kernel(const float* __restrict__ h, const int* __restrict__ perm,
                              const float* __restrict__ topv, float* __restrict__ xn, int rows) {
    int idx = blockIdx.x * blockDim.x + threadIdx.x;
    if (idx >= rows * FD) return;
    int r = idx >> 7;
    xn[idx] = h[(long long)perm[r] * FD + (idx & 127)] * topv[r];
}

// ---------------- edge remap through pooling ----------------
__global__ void remap_first_kernel(const int* __restrict__ ei, const int* __restrict__ mapping,
                                   int* __restrict__ src, int* __restrict__ dst,
                                   float* __restrict__ em, int E) {
    int e = blockIdx.x * blockDim.x + threadIdx.x;
    if (e >= E) return;
    int ns = mapping[ei[e]], nd = mapping[ei[E + e]];
    bool keep = (ns >= 0) && (nd >= 0);
    em[e]  = keep ? 1.0f : 0.0f;
    src[e] = ns > 0 ? ns : 0;
    dst[e] = nd > 0 ? nd : 0;
}

__global__ void remap_kernel(const int* __restrict__ mapping, int* __restrict__ src,
                             int* __restrict__ dst, float* __restrict__ em, int E) {
    int e = blockIdx.x * blockDim.x + threadIdx.x;
    if (e >= E) return;
    int ns = mapping[src[e]], nd = mapping[dst[e]];
    bool keep = (em[e] != 0.0f) && (ns >= 0) && (nd >= 0);
    em[e]  = keep ? 1.0f : 0.0f;
    src[e] = ns > 0 ? ns : 0;
    dst[e] = nd > 0 ? nd : 0;
}

// ---------------- readout: z[b] += [max || mean] over k nodes ----------------
__global__ void readout_kernel(const float* __restrict__ xk, int k, float* __restrict__ z) {
    int b = blockIdx.x, c = threadIdx.x;   // 128 threads
    const float* p = xk + (long long)b * k * FD + c;
    float mx = -INFINITY, sm = 0.0f;
    for (int i = 0; i < k; ++i) {
        float v = p[(long long)i * FD];
        mx = fmaxf(mx, v);
        sm += v;
    }
    z[b * 256 + c]       += mx;
    z[b * 256 + 128 + c] += sm / (float)k;
}

// ---------------- MLP head + log_softmax, one block per graph ----------------
__global__ __launch_bounds__(256) void head_kernel(const float* __restrict__ z,
        const float* __restrict__ W1, const float* __restrict__ b1,
        const float* __restrict__ W2, const float* __restrict__ b2,
        const float* __restrict__ W3, const float* __restrict__ b3,
        float* __restrict__ out) {
    __shared__ float zs[256], t1[128], t2[64], t3[16];
    int b = blockIdx.x, t = threadIdx.x;
    zs[t] = z[b * 256 + t];
    __syncthreads();
    if (t < 128) {
        float a = b1[t];
        for (int k = 0; k < 256; k++) a += zs[k] * W1[k * 128 + t];
        t1[t] = fmaxf(a, 0.0f);
    }
    __syncthreads();
    if (t < 64) {
        float a = b2[t];
        for (int k = 0; k < 128; k++) a += t1[k] * W2[k * 64 + t];
        t2[t] = fmaxf(a, 0.0f);
    }
    __syncthreads();
    if (t < 10) {
        float a = b3[t];
        for (int k = 0; k < 64; k++) a += t2[k] * W3[k * 10 + t];
        t3[t] = a;
    }
    __syncthreads();
    if (t == 0) {
        float m = -INFINITY;
        for (int i = 0; i < 10; i++) m = fmaxf(m, t3[i]);
        float s = 0.0f;
        for (int i = 0; i < 10; i++) s += expf(t3[i] - m);
        float ls = logf(s);
        for (int i = 0; i < 10; i++) out[b * 10 + i] = t3[i] - m - ls;
    }
}

extern "C" void kernel_launch(void* const* d_in, const int* in_sizes, int n_in,
                              void* d_out, int out_size, void* d_ws, size_t ws_size,
                              hipStream_t stream) {
    (void)in_sizes; (void)n_in; (void)out_size; (void)ws_size;
    const float* x   = (const float*)d_in[0];
    const int*   ei  = (const int*)d_in[1];
    const float* Wl1 = (const float*)d_in[2];
    const float* bl1 = (const float*)d_in[3];
    const float* Wr1 = (const float*)d_in[4];
    const float* Wl2 = (const float*)d_in[5];
    const float* bl2 = (const float*)d_in[6];
    const float* Wr2 = (const float*)d_in[7];
    const float* Wl3 = (const float*)d_in[8];
    const float* bl3 = (const float*)d_in[9];
    const float* Wr3 = (const float*)d_in[10];
    const float* pw1 = (const float*)d_in[11];
    const float* pw2 = (const float*)d_in[12];
    const float* pw3 = (const float*)d_in[13];
    const float* W1  = (const float*)d_in[14];
    const float* b1  = (const float*)d_in[15];
    const float* W2  = (const float*)d_in[16];
    const float* b2  = (const float*)d_in[17];
    const float* W3  = (const float*)d_in[18];
    const float* b3  = (const float*)d_in[19];
    float* out = (float*)d_out;

    // workspace layout (~72 MB)
    char* ws = (char*)d_ws;
    size_t off = 0;
    auto alloc = [&](size_t bytes) {
        char* p = ws + off;
        off = (off + bytes + 255) & ~(size_t)255;
        return p;
    };
    float* agg   = (float*)alloc((size_t)NN * FD * 4);
    float* hout  = (float*)alloc((size_t)NN * FD * 4);
    float* xp    = (float*)alloc((size_t)BG * K1 * FD * 4);
    float* cnt   = (float*)alloc((size_t)NN * 4);
    float* sc    = (float*)alloc((size_t)NN * 4);
    int*   mapg  = (int*)  alloc((size_t)NN * 4);
    int*   perm  = (int*)  alloc((size_t)BG * K1 * 4);
    float* topv  = (float*)alloc((size_t)BG * K1 * 4);
    int*   srcb  = (int*)  alloc((size_t)EE * 4);
    int*   dstb  = (int*)  alloc((size_t)EE * 4);
    float* emb   = (float*)alloc((size_t)EE * 4);
    float* z     = (float*)alloc((size_t)BG * 256 * 4);

    hipMemsetAsync(z, 0, (size_t)BG * 256 * 4, stream);

    // ================= layer 1 =================
    hipMemsetAsync(agg, 0, (size_t)NN * FD * 4, stream);
    hipMemsetAsync(cnt, 0, (size_t)NN * 4, stream);
    scatter_first_kernel<<<(EE * 32 + 255) / 256, 256, 0, stream>>>(ei, x, agg, cnt, EE);
    cntinv_kernel<<<(NN + 255) / 256, 256, 0, stream>>>(cnt, NN);
    sage_gemm_kernel<<<(NN + 63) / 64, 256, 0, stream>>>(agg, cnt, x, Wl1, Wr1, bl1, hout, NN);
    score_kernel<<<(NN * 64 + 255) / 256, 256, 0, stream>>>(hout, pw1, sc, NN);
    hipMemsetAsync(mapg, 0xFF, (size_t)NN * 4, stream);
    topk_kernel<<<BG, 256, 0, stream>>>(sc, NPG, K1, 512, perm, topv, mapg);
    gather_kernel<<<(BG * K1 * FD + 255) / 256, 256, 0, stream>>>(hout, perm, topv, xp, BG * K1);
    readout_kernel<<<BG, 128, 0, stream>>>(xp, K1, z);
    remap_first_kernel<<<(EE + 255) / 256, 256, 0, stream>>>(ei, mapg, srcb, dstb, emb, EE);

    // ================= layer 2 =================
    const int N2 = BG * K1;   // 25000
    hipMemsetAsync(agg, 0, (size_t)N2 * FD * 4, stream);
    hipMemsetAsync(cnt, 0, (size_t)N2 * 4, stream);
    scatter_masked_kernel<<<(EE * 32 + 255) / 256, 256, 0, stream>>>(srcb, dstb, emb, xp, agg, cnt, EE);
    cntinv_kernel<<<(N2 + 255) / 256, 256, 0, stream>>>(cnt, N2);
    sage_gemm_kernel<<<(N2 + 63) / 64, 256, 0, stream>>>(agg, cnt, xp, Wl2, Wr2, bl2, hout, N2);
    score_kernel<<<(N2 * 64 + 255) / 256, 256, 0, stream>>>(hout, pw2, sc, N2);
    hipMemsetAsync(mapg, 0xFF, (size_t)N2 * 4, stream);
    topk_kernel<<<BG, 256, 0, stream>>>(sc, K1, K2, 256, perm, topv, mapg);
    gather_kernel<<<(BG * K2 * FD + 255) / 256, 256, 0, stream>>>(hout, perm, topv, xp, BG * K2);
    readout_kernel<<<BG, 128, 0, stream>>>(xp, K2, z);
    remap_kernel<<<(EE + 255) / 256, 256, 0, stream>>>(mapg, srcb, dstb, emb, EE);

    // ================= layer 3 =================
    const int N3 = BG * K2;   // 12500
    hipMemsetAsync(agg, 0, (size_t)N3 * FD * 4, stream);
    hipMemsetAsync(cnt, 0, (size_t)N3 * 4, stream);
    scatter_masked_kernel<<<(EE * 32 + 255) / 256, 256, 0, stream>>>(srcb, dstb, emb, xp, agg, cnt, EE);
    cntinv_kernel<<<(N3 + 255) / 256, 256, 0, stream>>>(cnt, N3);
    sage_gemm_kernel<<<(N3 + 63) / 64, 256, 0, stream>>>(agg, cnt, xp, Wl3, Wr3, bl3, hout, N3);
    score_kernel<<<(N3 * 64 + 255) / 256, 256, 0, stream>>>(hout, pw3, sc, N3);
    hipMemsetAsync(mapg, 0xFF, (size_t)N3 * 4, stream);
    topk_kernel<<<BG, 256, 0, stream>>>(sc, K2, K3, 128, perm, topv, mapg);
    gather_kernel<<<(BG * K3 * FD + 255) / 256, 256, 0, stream>>>(hout, perm, topv, xp, BG * K3);
    readout_kernel<<<BG, 128, 0, stream>>>(xp, K3, z);
    // final edge remap is dead code in the reference (edges unused after layer 3) -> skipped

    // ================= head =================
    head_kernel<<<BG, 256, 0, stream>>>(z, W1, b1, W2, b2, W3, b3, out);
}

// Round 2
// 722.694 us; speedup vs baseline: 2.5717x; 2.5717x over previous
//
#include <hip/hip_runtime.h>
#include <math.h>

// Problem constants (from reference)
#define BG    100        // graphs
#define NPG   500        // nodes per graph (layer 1)
#define FD    128        // feature dim (F_IN == H == 128)
#define EE    600000     // edges
#define NN    50000      // total nodes layer 1
#define K1    250
#define K2    125
#define K3    63

// ---------------- CSR build ----------------
__global__ void count_first_kernel(const int* __restrict__ ei, int* __restrict__ deg, int E) {
    int e = blockIdx.x * blockDim.x + threadIdx.x;
    if (e >= E) return;
    atomicAdd(&deg[ei[E + e]], 1);
}

// remap edges through pooling AND count new in-degrees (first layer: from edge_index)
__global__ void remap_first_count_kernel(const int* __restrict__ ei, const int* __restrict__ mapping,
                                         int* __restrict__ src, int* __restrict__ dst,
                                         float* __restrict__ em, int* __restrict__ deg, int E) {
    int e = blockIdx.x * blockDim.x + threadIdx.x;
    if (e >= E) return;
    int ns = mapping[ei[e]], nd = mapping[ei[E + e]];
    bool keep = (ns >= 0) && (nd >= 0);
    em[e]  = keep ? 1.0f : 0.0f;
    src[e] = keep ? ns : 0;
    dst[e] = keep ? nd : 0;
    if (keep) atomicAdd(&deg[nd], 1);
}

__global__ void remap_count_kernel(const int* __restrict__ mapping, int* __restrict__ src,
                                   int* __restrict__ dst, float* __restrict__ em,
                                   int* __restrict__ deg, int E) {
    int e = blockIdx.x * blockDim.x + threadIdx.x;
    if (e >= E) return;
    float m = em[e];
    int ns = mapping[src[e]], nd = mapping[dst[e]];
    bool keep = (m != 0.0f) && (ns >= 0) && (nd >= 0);
    em[e]  = keep ? 1.0f : 0.0f;
    src[e] = keep ? ns : 0;
    dst[e] = keep ? nd : 0;
    if (keep) atomicAdd(&deg[nd], 1);
}

// single-block exclusive scan: rowptr[0]=0, rowptr[i+1]=sum(deg[0..i])
__global__ __launch_bounds__(1024) void exscan_kernel(const int* __restrict__ deg,
                                                      int* __restrict__ rowptr, int n) {
    __shared__ int sdata[1024];
    __shared__ int soff;
    int tid = threadIdx.x;
    if (tid == 0) { soff = 0; rowptr[0] = 0; }
    __syncthreads();
    for (int base = 0; base < n; base += 1024) {
        int i = base + tid;
        int v = (i < n) ? deg[i] : 0;
        sdata[tid] = v;
        __syncthreads();
        for (int s = 1; s < 1024; s <<= 1) {
            int t = (tid >= s) ? sdata[tid - s] : 0;
            __syncthreads();
            sdata[tid] += t;
            __syncthreads();
        }
        if (i < n) rowptr[i + 1] = soff + sdata[tid];
        __syncthreads();
        if (tid == 0) soff += sdata[1023];
        __syncthreads();
    }
}

// fill neighbor lists; uses deg[] as a countdown cursor (atomicSub), leaves deg=0
__global__ void fill_first_kernel(const int* __restrict__ ei, int* __restrict__ deg,
                                  const int* __restrict__ rowptr, int* __restrict__ col, int E) {
    int e = blockIdx.x * blockDim.x + threadIdx.x;
    if (e >= E) return;
    int d = ei[E + e];
    int old = atomicSub(&deg[d], 1);
    col[rowptr[d + 1] - old] = ei[e];
}

__global__ void fill_masked_kernel(const int* __restrict__ src, const int* __restrict__ dst,
                                   const float* __restrict__ em, int* __restrict__ deg,
                                   const int* __restrict__ rowptr, int* __restrict__ col, int E) {
    int e = blockIdx.x * blockDim.x + threadIdx.x;
    if (e >= E) return;
    if (em[e] == 0.0f) return;
    int d = dst[e];
    int old = atomicSub(&deg[d], 1);
    col[rowptr[d + 1] - old] = src[e];
}

// ---------------- gather-aggregate: mean of neighbor rows, one wave per node ----------------
__global__ void gather_agg_kernel(const int* __restrict__ rowptr, const int* __restrict__ col,
                                  const float* __restrict__ x, float* __restrict__ mean, int n) {
    int g = blockIdx.x * blockDim.x + threadIdx.x;
    int node = g >> 6, lane = g & 63;
    if (node >= n) return;
    int r0 = rowptr[node], r1 = rowptr[node + 1];
    float ax = 0.0f, ay = 0.0f;
    for (int j = r0; j < r1; ++j) {
        int s = col[j];
        float2 v = ((const float2*)(x + (long long)s * FD))[lane];
        ax += v.x; ay += v.y;
    }
    float inv = 1.0f / fmaxf((float)(r1 - r0), 1.0f);
    float2 o; o.x = ax * inv; o.y = ay * inv;
    ((float2*)(mean + (long long)node * FD))[lane] = o;
}

// ---------------- fused SAGE GEMM: relu(mean@Wl + x@Wr + bl) ----------------
// Tile: 64 rows x 128 cols, K=256 logical (mean | x), k-tile 32.
__global__ __launch_bounds__(256) void sage_gemm_kernel(
        const float* __restrict__ mean, const float* __restrict__ x,
        const float* __restrict__ Wl, const float* __restrict__ Wr,
        const float* __restrict__ bl, float* __restrict__ hout, int M) {
    __shared__ float As[32 * 64];    // [kk][row]
    __shared__ float Ws[32 * 128];   // [kk][col]
    int tid  = threadIdx.x;
    int row0 = blockIdx.x * 64;
    int tr   = tid >> 4;
    int tc   = tid & 15;
    float acc[4][8];
#pragma unroll
    for (int r = 0; r < 4; r++)
#pragma unroll
        for (int c = 0; c < 8; c++) acc[r][c] = 0.0f;

    int lrow = tid >> 3;             // 0..31
    int lk   = (tid & 7) * 4;        // 0,4,..,28

    for (int kt = 0; kt < 8; ++kt) {
        bool isMean = kt < 4;
        int kcol = (isMean ? kt * 32 : (kt - 4) * 32) + lk;
        const float* Ab = isMean ? mean : x;
#pragma unroll
        for (int p = 0; p < 2; ++p) {
            int row  = p * 32 + lrow;
            int grow = row0 + row; if (grow > M - 1) grow = M - 1;
            float4 v = *(const float4*)(Ab + (long long)grow * FD + kcol);
            As[(lk + 0) * 64 + row] = v.x;
            As[(lk + 1) * 64 + row] = v.y;
            As[(lk + 2) * 64 + row] = v.z;
            As[(lk + 3) * 64 + row] = v.w;
        }
        {
            int wc  = (tid & 31) * 4;
            int wk0 = tid >> 5;
            const float* WB = isMean ? Wl : Wr;
            int krow0 = isMean ? kt * 32 : (kt - 4) * 32;
#pragma unroll
            for (int q = 0; q < 4; ++q) {
                int kk = wk0 + q * 8;
                float4 v = *(const float4*)(WB + (long long)(krow0 + kk) * FD + wc);
                *(float4*)&Ws[kk * 128 + wc] = v;
            }
        }
        __syncthreads();
#pragma unroll
        for (int kk = 0; kk < 32; ++kk) {
            float4 a  = *(const float4*)&As[kk * 64 + tr * 4];
            float4 b0 = *(const float4*)&Ws[kk * 128 + tc * 8];
            float4 b1 = *(const float4*)&Ws[kk * 128 + tc * 8 + 4];
            float av[4] = {a.x, a.y, a.z, a.w};
            float bv[8] = {b0.x, b0.y, b0.z, b0.w, b1.x, b1.y, b1.z, b1.w};
#pragma unroll
            for (int r = 0; r < 4; r++)
#pragma unroll
                for (int c = 0; c < 8; c++) acc[r][c] += av[r] * bv[c];
        }
        __syncthreads();
    }
    float bvec[8];
#pragma unroll
    for (int c = 0; c < 8; c++) bvec[c] = bl[tc * 8 + c];
#pragma unroll
    for (int r = 0; r < 4; r++) {
        int grow = row0 + tr * 4 + r;
        if (grow < M) {
            float* dstp = hout + (long long)grow * FD + tc * 8;
#pragma unroll
            for (int c = 0; c < 8; c++) dstp[c] = fmaxf(acc[r][c] + bvec[c], 0.0f);
        }
    }
}

// ---------------- score = tanh(h.w / ||w||), one wave per node ----------------
__global__ void score_kernel(const float* __restrict__ h, const float* __restrict__ w,
                             float* __restrict__ score, int n) {
    int g = blockIdx.x * blockDim.x + threadIdx.x;
    int node = g >> 6, lane = g & 63;
    if (node >= n) return;
    float2 wv = ((const float2*)w)[lane];
    float2 xv = ((const float2*)(h + (long long)node * FD))[lane];
    float dot = xv.x * wv.x + xv.y * wv.y;
    float nrm = wv.x * wv.x + wv.y * wv.y;
    for (int off = 32; off; off >>= 1) {
        dot += __shfl_down(dot, off);
        nrm += __shfl_down(nrm, off);
    }
    if (lane == 0) score[node] = tanhf(dot / sqrtf(nrm));
}

// ---------------- per-graph top-k (bitonic sort in LDS, jax.lax.top_k order) ----------------
__global__ __launch_bounds__(256) void topk_kernel(const float* __restrict__ score,
        int n_per, int k, int SN, int* __restrict__ perm, float* __restrict__ topv,
        int* __restrict__ mapping) {
    __shared__ float skey[512];
    __shared__ int   sidx[512];
    int b = blockIdx.x, tid = threadIdx.x;
    for (int i = tid; i < SN; i += 256) {
        if (i < n_per) { skey[i] = score[b * n_per + i]; sidx[i] = i; }
        else           { skey[i] = -INFINITY;            sidx[i] = 0x7fffffff; }
    }
    __syncthreads();
    for (int ks = 2; ks <= SN; ks <<= 1) {
        for (int j = ks >> 1; j > 0; j >>= 1) {
            for (int i = tid; i < SN; i += 256) {
                int l = i ^ j;
                if (l > i) {
                    float ki = skey[i], kl = skey[l];
                    int   ii = sidx[i], il = sidx[l];
                    bool before = (ki > kl) || (ki == kl && ii < il);
                    bool up = ((i & ks) == 0);
                    if (up ? !before : before) {
                        skey[i] = kl; skey[l] = ki;
                        sidx[i] = il; sidx[l] = ii;
                    }
                }
            }
            __syncthreads();
        }
    }
    for (int i = tid; i < k; i += 256) {
        int old  = sidx[i];
        int oldg = b * n_per + old;
        int newg = b * k + i;
        perm[newg] = oldg;
        topv[newg] = skey[i];
        mapping[oldg] = newg;
    }
}

// ---------------- gather + scale: x_new = h[perm] * topv ----------------
__global__ void gather_kernel(const float* __restrict__ h, const int* __restrict__ perm,
                              const float* __restrict__ topv, float* __restrict__ xn, int rows) {
    int idx = blockIdx.x * blockDim.x + threadIdx.x;
    if (idx >= rows * FD) return;
    int r = idx >> 7;
    xn[idx] = h[(long long)perm[r] * FD + (idx & 127)] * topv[r];
}

// ---------------- readout: z[b] += [max || mean] over k nodes ----------------
__global__ void readout_kernel(const float* __restrict__ xk, int k, float* __restrict__ z) {
    int b = blockIdx.x, c = threadIdx.x;   // 128 threads
    const float* p = xk + (long long)b * k * FD + c;
    float mx = -INFINITY, sm = 0.0f;
    for (int i = 0; i < k; ++i) {
        float v = p[(long long)i * FD];
        mx = fmaxf(mx, v);
        sm += v;
    }
    z[b * 256 + c]       += mx;
    z[b * 256 + 128 + c] += sm / (float)k;
}

// ---------------- MLP head + log_softmax, one block per graph ----------------
__global__ __launch_bounds__(256) void head_kernel(const float* __restrict__ z,
        const float* __restrict__ W1, const float* __restrict__ b1,
        const float* __restrict__ W2, const float* __restrict__ b2,
        const float* __restrict__ W3, const float* __restrict__ b3,
        float* __restrict__ out) {
    __shared__ float zs[256], t1[128], t2[64], t3[16];
    int b = blockIdx.x, t = threadIdx.x;
    zs[t] = z[b * 256 + t];
    __syncthreads();
    if (t < 128) {
        float a = b1[t];
        for (int k = 0; k < 256; k++) a += zs[k] * W1[k * 128 + t];
        t1[t] = fmaxf(a, 0.0f);
    }
    __syncthreads();
    if (t < 64) {
        float a = b2[t];
        for (int k = 0; k < 128; k++) a += t1[k] * W2[k * 64 + t];
        t2[t] = fmaxf(a, 0.0f);
    }
    __syncthreads();
    if (t < 10) {
        float a = b3[t];
        for (int k = 0; k < 64; k++) a += t2[k] * W3[k * 10 + t];
        t3[t] = a;
    }
    __syncthreads();
    if (t == 0) {
        float m = -INFINITY;
        for (int i = 0; i < 10; i++) m = fmaxf(m, t3[i]);
        float s = 0.0f;
        for (int i = 0; i < 10; i++) s += expf(t3[i] - m);
        float ls = logf(s);
        for (int i = 0; i < 10; i++) out[b * 10 + i] = t3[i] - m - ls;
    }
}

extern "C" void kernel_launch(void* const* d_in, const int* in_sizes, int n_in,
                              void* d_out, int out_size, void* d_ws, size_t ws_size,
                              hipStream_t stream) {
    (void)in_sizes; (void)n_in; (void)out_size; (void)ws_size;
    const float* x   = (const float*)d_in[0];
    const int*   ei  = (const int*)d_in[1];
    const float* Wl1 = (const float*)d_in[2];
    const float* bl1 = (const float*)d_in[3];
    const float* Wr1 = (const float*)d_in[4];
    const float* Wl2 = (const float*)d_in[5];
    const float* bl2 = (const float*)d_in[6];
    const float* Wr2 = (const float*)d_in[7];
    const float* Wl3 = (const float*)d_in[8];
    const float* bl3 = (const float*)d_in[9];
    const float* Wr3 = (const float*)d_in[10];
    const float* pw1 = (const float*)d_in[11];
    const float* pw2 = (const float*)d_in[12];
    const float* pw3 = (const float*)d_in[13];
    const float* W1  = (const float*)d_in[14];
    const float* b1  = (const float*)d_in[15];
    const float* W2  = (const float*)d_in[16];
    const float* b2  = (const float*)d_in[17];
    const float* W3  = (const float*)d_in[18];
    const float* b3  = (const float*)d_in[19];
    float* out = (float*)d_out;

    // workspace layout
    char* ws = (char*)d_ws;
    size_t off = 0;
    auto alloc = [&](size_t bytes) {
        char* p = ws + off;
        off = (off + bytes + 255) & ~(size_t)255;
        return p;
    };
    float* mean  = (float*)alloc((size_t)NN * FD * 4);
    float* hout  = (float*)alloc((size_t)NN * FD * 4);
    float* xp    = (float*)alloc((size_t)BG * K1 * FD * 4);
    float* sc    = (float*)alloc((size_t)NN * 4);
    int*   mapg  = (int*)  alloc((size_t)NN * 4);
    int*   perm  = (int*)  alloc((size_t)BG * K1 * 4);
    float* topv  = (float*)alloc((size_t)BG * K1 * 4);
    int*   srcb  = (int*)  alloc((size_t)EE * 4);
    int*   dstb  = (int*)  alloc((size_t)EE * 4);
    float* emb   = (float*)alloc((size_t)EE * 4);
    int*   deg   = (int*)  alloc((size_t)NN * 4);
    int*   rowptr= (int*)  alloc((size_t)(NN + 1) * 4);
    int*   colb  = (int*)  alloc((size_t)EE * 4);
    float* z     = (float*)alloc((size_t)BG * 256 * 4);

    hipMemsetAsync(z, 0, (size_t)BG * 256 * 4, stream);

    const int EB = (EE + 255) / 256;

    // ================= layer 1 =================
    hipMemsetAsync(deg, 0, (size_t)NN * 4, stream);
    count_first_kernel<<<EB, 256, 0, stream>>>(ei, deg, EE);
    exscan_kernel<<<1, 1024, 0, stream>>>(deg, rowptr, NN);
    fill_first_kernel<<<EB, 256, 0, stream>>>(ei, deg, rowptr, colb, EE);
    gather_agg_kernel<<<(NN * 64 + 255) / 256, 256, 0, stream>>>(rowptr, colb, x, mean, NN);
    sage_gemm_kernel<<<(NN + 63) / 64, 256, 0, stream>>>(mean, x, Wl1, Wr1, bl1, hout, NN);
    score_kernel<<<(NN * 64 + 255) / 256, 256, 0, stream>>>(hout, pw1, sc, NN);
    hipMemsetAsync(mapg, 0xFF, (size_t)NN * 4, stream);
    topk_kernel<<<BG, 256, 0, stream>>>(sc, NPG, K1, 512, perm, topv, mapg);
    gather_kernel<<<(BG * K1 * FD + 255) / 256, 256, 0, stream>>>(hout, perm, topv, xp, BG * K1);
    readout_kernel<<<BG, 128, 0, stream>>>(xp, K1, z);

    // ================= layer 2 =================
    const int N2 = BG * K1;   // 25000
    hipMemsetAsync(deg, 0, (size_t)N2 * 4, stream);
    remap_first_count_kernel<<<EB, 256, 0, stream>>>(ei, mapg, srcb, dstb, emb, deg, EE);
    exscan_kernel<<<1, 1024, 0, stream>>>(deg, rowptr, N2);
    fill_masked_kernel<<<EB, 256, 0, stream>>>(srcb, dstb, emb, deg, rowptr, colb, EE);
    gather_agg_kernel<<<(N2 * 64 + 255) / 256, 256, 0, stream>>>(rowptr, colb, xp, mean, N2);
    sage_gemm_kernel<<<(N2 + 63) / 64, 256, 0, stream>>>(mean, xp, Wl2, Wr2, bl2, hout, N2);
    score_kernel<<<(N2 * 64 + 255) / 256, 256, 0, stream>>>(hout, pw2, sc, N2);
    hipMemsetAsync(mapg, 0xFF, (size_t)N2 * 4, stream);
    topk_kernel<<<BG, 256, 0, stream>>>(sc, K1, K2, 256, perm, topv, mapg);
    gather_kernel<<<(BG * K2 * FD + 255) / 256, 256, 0, stream>>>(hout, perm, topv, xp, BG * K2);
    readout_kernel<<<BG, 128, 0, stream>>>(xp, K2, z);

    // ================= layer 3 =================
    const int N3 = BG * K2;   // 12500
    hipMemsetAsync(deg, 0, (size_t)N3 * 4, stream);
    remap_count_kernel<<<EB, 256, 0, stream>>>(mapg, srcb, dstb, emb, deg, EE);
    exscan_kernel<<<1, 1024, 0, stream>>>(deg, rowptr, N3);
    fill_masked_kernel<<<EB, 256, 0, stream>>>(srcb, dstb, emb, deg, rowptr, colb, EE);
    gather_agg_kernel<<<(N3 * 64 + 255) / 256, 256, 0, stream>>>(rowptr, colb, xp, mean, N3);
    sage_gemm_kernel<<<(N3 + 63) / 64, 256, 0, stream>>>(mean, xp, Wl3, Wr3, bl3, hout, N3);
    score_kernel<<<(N3 * 64 + 255) / 256, 256, 0, stream>>>(hout, pw3, sc, N3);
    hipMemsetAsync(mapg, 0xFF, (size_t)N3 * 4, stream);
    topk_kernel<<<BG, 256, 0, stream>>>(sc, K2, K3, 128, perm, topv, mapg);
    gather_kernel<<<(BG * K3 * FD + 255) / 256, 256, 0, stream>>>(hout, perm, topv, xp, BG * K3);
    readout_kernel<<<BG, 128, 0, stream>>>(xp, K3, z);

    // ================= head =================
    head_kernel<<<BG, 256, 0, stream>>>(z, W1, b1, W2, b2, W3, b3, out);
}

// Round 3
// 544.523 us; speedup vs baseline: 3.4132x; 1.3272x over previous
//
#include <hip/hip_runtime.h>
#include <math.h>

// Problem constants (from reference)
#define BG    100        // graphs
#define NPG   500        // nodes per graph (layer 1)
#define FD    128        // feature dim (F_IN == H == 128)
#define EE    600000     // edges
#define NN    50000      // total nodes layer 1
#define K1    250
#define K2    125
#define K3    63
#define CAP   64         // max in-degree capacity (in-deg ~ Poisson(12); P(>64) ~ 1e-30)

// ---------------- slot-CSR build: one edge pass, no scan ----------------
__global__ void fill_first_kernel(const int* __restrict__ ei, int* __restrict__ deg,
                                  int* __restrict__ col, int E) {
    int e = blockIdx.x * blockDim.x + threadIdx.x;
    if (e >= E) return;
    int d = ei[E + e];
    int pos = atomicAdd(&deg[d], 1);
    if (pos < CAP) col[d * CAP + pos] = ei[e];
}

// remap original edges through layer-1 pooling, store remapped edges for layer 3,
// and fill layer-2 neighbor slots — all in one pass
__global__ void remap_fill_first_kernel(const int* __restrict__ ei, const int* __restrict__ mapping,
                                        int* __restrict__ src, int* __restrict__ dst,
                                        float* __restrict__ em, int* __restrict__ deg,
                                        int* __restrict__ col, int E) {
    int e = blockIdx.x * blockDim.x + threadIdx.x;
    if (e >= E) return;
    int ns = mapping[ei[e]], nd = mapping[ei[E + e]];
    bool keep = (ns >= 0) && (nd >= 0);
    em[e]  = keep ? 1.0f : 0.0f;
    src[e] = keep ? ns : 0;
    dst[e] = keep ? nd : 0;
    if (keep) {
        int pos = atomicAdd(&deg[nd], 1);
        if (pos < CAP) col[nd * CAP + pos] = ns;
    }
}

// remap layer-2 edges through layer-2 pooling and fill layer-3 slots (no store-back needed)
__global__ void remap_fill_kernel(const int* __restrict__ src, const int* __restrict__ dst,
                                  const float* __restrict__ em, const int* __restrict__ mapping,
                                  int* __restrict__ deg, int* __restrict__ col, int E) {
    int e = blockIdx.x * blockDim.x + threadIdx.x;
    if (e >= E) return;
    if (em[e] == 0.0f) return;
    int ns = mapping[src[e]], nd = mapping[dst[e]];
    if (ns >= 0 && nd >= 0) {
        int pos = atomicAdd(&deg[nd], 1);
        if (pos < CAP) col[nd * CAP + pos] = ns;
    }
}

// ---------------- gather-aggregate: mean of neighbor rows, one wave per node ----------------
__global__ void gather_agg_kernel(const int* __restrict__ deg, const int* __restrict__ col,
                                  const float* __restrict__ x, float* __restrict__ mean, int n) {
    int g = blockIdx.x * blockDim.x + threadIdx.x;
    int node = g >> 6, lane = g & 63;
    if (node >= n) return;
    int d = deg[node]; if (d > CAP) d = CAP;
    const int* cp = col + node * CAP;
    float ax = 0.0f, ay = 0.0f;
    for (int j = 0; j < d; ++j) {
        int s = cp[j];
        float2 v = ((const float2*)(x + (long long)s * FD))[lane];
        ax += v.x; ay += v.y;
    }
    float inv = 1.0f / fmaxf((float)d, 1.0f);
    float2 o; o.x = ax * inv; o.y = ay * inv;
    ((float2*)(mean + (long long)node * FD))[lane] = o;
}

// ---------------- fused SAGE GEMM: relu(mean@Wl + x@Wr + bl) ----------------
// Tile: 64 rows x 128 cols, K=256 logical (mean | x), k-tile 32.
__global__ __launch_bounds__(256) void sage_gemm_kernel(
        const float* __restrict__ mean, const float* __restrict__ x,
        const float* __restrict__ Wl, const float* __restrict__ Wr,
        const float* __restrict__ bl, float* __restrict__ hout, int M) {
    __shared__ float As[32 * 64];    // [kk][row]
    __shared__ float Ws[32 * 128];   // [kk][col]
    int tid  = threadIdx.x;
    int row0 = blockIdx.x * 64;
    int tr   = tid >> 4;
    int tc   = tid & 15;
    float acc[4][8];
#pragma unroll
    for (int r = 0; r < 4; r++)
#pragma unroll
        for (int c = 0; c < 8; c++) acc[r][c] = 0.0f;

    int lrow = tid >> 3;             // 0..31
    int lk   = (tid & 7) * 4;        // 0,4,..,28

    for (int kt = 0; kt < 8; ++kt) {
        bool isMean = kt < 4;
        int kcol = (isMean ? kt * 32 : (kt - 4) * 32) + lk;
        const float* Ab = isMean ? mean : x;
#pragma unroll
        for (int p = 0; p < 2; ++p) {
            int row  = p * 32 + lrow;
            int grow = row0 + row; if (grow > M - 1) grow = M - 1;
            float4 v = *(const float4*)(Ab + (long long)grow * FD + kcol);
            As[(lk + 0) * 64 + row] = v.x;
            As[(lk + 1) * 64 + row] = v.y;
            As[(lk + 2) * 64 + row] = v.z;
            As[(lk + 3) * 64 + row] = v.w;
        }
        {
            int wc  = (tid & 31) * 4;
            int wk0 = tid >> 5;
            const float* WB = isMean ? Wl : Wr;
            int krow0 = isMean ? kt * 32 : (kt - 4) * 32;
#pragma unroll
            for (int q = 0; q < 4; ++q) {
                int kk = wk0 + q * 8;
                float4 v = *(const float4*)(WB + (long long)(krow0 + kk) * FD + wc);
                *(float4*)&Ws[kk * 128 + wc] = v;
            }
        }
        __syncthreads();
#pragma unroll
        for (int kk = 0; kk < 32; ++kk) {
            float4 a  = *(const float4*)&As[kk * 64 + tr * 4];
            float4 b0 = *(const float4*)&Ws[kk * 128 + tc * 8];
            float4 b1 = *(const float4*)&Ws[kk * 128 + tc * 8 + 4];
            float av[4] = {a.x, a.y, a.z, a.w};
            float bv[8] = {b0.x, b0.y, b0.z, b0.w, b1.x, b1.y, b1.z, b1.w};
#pragma unroll
            for (int r = 0; r < 4; r++)
#pragma unroll
                for (int c = 0; c < 8; c++) acc[r][c] += av[r] * bv[c];
        }
        __syncthreads();
    }
    float bvec[8];
#pragma unroll
    for (int c = 0; c < 8; c++) bvec[c] = bl[tc * 8 + c];
#pragma unroll
    for (int r = 0; r < 4; r++) {
        int grow = row0 + tr * 4 + r;
        if (grow < M) {
            float* dstp = hout + (long long)grow * FD + tc * 8;
#pragma unroll
            for (int c = 0; c < 8; c++) dstp[c] = fmaxf(acc[r][c] + bvec[c], 0.0f);
        }
    }
}

// ---------------- score = tanh(h.w / ||w||), one wave per node ----------------
__global__ void score_kernel(const float* __restrict__ h, const float* __restrict__ w,
                             float* __restrict__ score, int n) {
    int g = blockIdx.x * blockDim.x + threadIdx.x;
    int node = g >> 6, lane = g & 63;
    if (node >= n) return;
    float2 wv = ((const float2*)w)[lane];
    float2 xv = ((const float2*)(h + (long long)node * FD))[lane];
    float dot = xv.x * wv.x + xv.y * wv.y;
    float nrm = wv.x * wv.x + wv.y * wv.y;
    for (int off = 32; off; off >>= 1) {
        dot += __shfl_down(dot, off);
        nrm += __shfl_down(nrm, off);
    }
    if (lane == 0) score[node] = tanhf(dot / sqrtf(nrm));
}

// ---------------- per-graph top-k (bitonic sort in LDS, jax.lax.top_k order) ----------------
__global__ __launch_bounds__(256) void topk_kernel(const float* __restrict__ score,
        int n_per, int k, int SN, int* __restrict__ perm, float* __restrict__ topv,
        int* __restrict__ mapping) {
    __shared__ float skey[512];
    __shared__ int   sidx[512];
    int b = blockIdx.x, tid = threadIdx.x;
    for (int i = tid; i < SN; i += 256) {
        if (i < n_per) { skey[i] = score[b * n_per + i]; sidx[i] = i; }
        else           { skey[i] = -INFINITY;            sidx[i] = 0x7fffffff; }
    }
    __syncthreads();
    for (int ks = 2; ks <= SN; ks <<= 1) {
        for (int j = ks >> 1; j > 0; j >>= 1) {
            for (int i = tid; i < SN; i += 256) {
                int l = i ^ j;
                if (l > i) {
                    float ki = skey[i], kl = skey[l];
                    int   ii = sidx[i], il = sidx[l];
                    bool before = (ki > kl) || (ki == kl && ii < il);
                    bool up = ((i & ks) == 0);
                    if (up ? !before : before) {
                        skey[i] = kl; skey[l] = ki;
                        sidx[i] = il; sidx[l] = ii;
                    }
                }
            }
            __syncthreads();
        }
    }
    for (int i = tid; i < k; i += 256) {
        int old  = sidx[i];
        int oldg = b * n_per + old;
        int newg = b * k + i;
        perm[newg] = oldg;
        topv[newg] = skey[i];
        mapping[oldg] = newg;
    }
}

// ---------------- gather + scale: x_new = h[perm] * topv ----------------
__global__ void gather_kernel(const float* __restrict__ h, const int* __restrict__ perm,
                              const float* __restrict__ topv, float* __restrict__ xn, int rows) {
    int idx = blockIdx.x * blockDim.x + threadIdx.x;
    if (idx >= rows * FD) return;
    int r = idx >> 7;
    xn[idx] = h[(long long)perm[r] * FD + (idx & 127)] * topv[r];
}

// ---------------- readout: z[b] += [max || mean] over k nodes ----------------
__global__ void readout_kernel(const float* __restrict__ xk, int k, float* __restrict__ z) {
    int b = blockIdx.x, c = threadIdx.x;   // 128 threads
    const float* p = xk + (long long)b * k * FD + c;
    float mx = -INFINITY, sm = 0.0f;
    for (int i = 0; i < k; ++i) {
        float v = p[(long long)i * FD];
        mx = fmaxf(mx, v);
        sm += v;
    }
    z[b * 256 + c]       += mx;
    z[b * 256 + 128 + c] += sm / (float)k;
}

// ---------------- MLP head + log_softmax, one block per graph ----------------
__global__ __launch_bounds__(256) void head_kernel(const float* __restrict__ z,
        const float* __restrict__ W1, const float* __restrict__ b1,
        const float* __restrict__ W2, const float* __restrict__ b2,
        const float* __restrict__ W3, const float* __restrict__ b3,
        float* __restrict__ out) {
    __shared__ float zs[256], t1[128], t2[64], t3[16];
    int b = blockIdx.x, t = threadIdx.x;
    zs[t] = z[b * 256 + t];
    __syncthreads();
    if (t < 128) {
        float a = b1[t];
        for (int k = 0; k < 256; k++) a += zs[k] * W1[k * 128 + t];
        t1[t] = fmaxf(a, 0.0f);
    }
    __syncthreads();
    if (t < 64) {
        float a = b2[t];
        for (int k = 0; k < 128; k++) a += t1[k] * W2[k * 64 + t];
        t2[t] = fmaxf(a, 0.0f);
    }
    __syncthreads();
    if (t < 10) {
        float a = b3[t];
        for (int k = 0; k < 64; k++) a += t2[k] * W3[k * 10 + t];
        t3[t] = a;
    }
    __syncthreads();
    if (t == 0) {
        float m = -INFINITY;
        for (int i = 0; i < 10; i++) m = fmaxf(m, t3[i]);
        float s = 0.0f;
        for (int i = 0; i < 10; i++) s += expf(t3[i] - m);
        float ls = logf(s);
        for (int i = 0; i < 10; i++) out[b * 10 + i] = t3[i] - m - ls;
    }
}

extern "C" void kernel_launch(void* const* d_in, const int* in_sizes, int n_in,
                              void* d_out, int out_size, void* d_ws, size_t ws_size,
                              hipStream_t stream) {
    (void)in_sizes; (void)n_in; (void)out_size; (void)ws_size;
    const float* x   = (const float*)d_in[0];
    const int*   ei  = (const int*)d_in[1];
    const float* Wl1 = (const float*)d_in[2];
    const float* bl1 = (const float*)d_in[3];
    const float* Wr1 = (const float*)d_in[4];
    const float* Wl2 = (const float*)d_in[5];
    const float* bl2 = (const float*)d_in[6];
    const float* Wr2 = (const float*)d_in[7];
    const float* Wl3 = (const float*)d_in[8];
    const float* bl3 = (const float*)d_in[9];
    const float* Wr3 = (const float*)d_in[10];
    const float* pw1 = (const float*)d_in[11];
    const float* pw2 = (const float*)d_in[12];
    const float* pw3 = (const float*)d_in[13];
    const float* W1  = (const float*)d_in[14];
    const float* b1  = (const float*)d_in[15];
    const float* W2  = (const float*)d_in[16];
    const float* b2  = (const float*)d_in[17];
    const float* W3  = (const float*)d_in[18];
    const float* b3  = (const float*)d_in[19];
    float* out = (float*)d_out;

    // workspace layout
    char* ws = (char*)d_ws;
    size_t off = 0;
    auto alloc = [&](size_t bytes) {
        char* p = ws + off;
        off = (off + bytes + 255) & ~(size_t)255;
        return p;
    };
    float* mean  = (float*)alloc((size_t)NN * FD * 4);
    float* hout  = (float*)alloc((size_t)NN * FD * 4);
    float* xp    = (float*)alloc((size_t)BG * K1 * FD * 4);
    float* sc    = (float*)alloc((size_t)NN * 4);
    int*   mapg  = (int*)  alloc((size_t)NN * 4);
    int*   perm  = (int*)  alloc((size_t)BG * K1 * 4);
    float* topv  = (float*)alloc((size_t)BG * K1 * 4);
    int*   srcb  = (int*)  alloc((size_t)EE * 4);
    int*   dstb  = (int*)  alloc((size_t)EE * 4);
    float* emb   = (float*)alloc((size_t)EE * 4);
    int*   deg   = (int*)  alloc((size_t)NN * 4);
    int*   colb  = (int*)  alloc((size_t)NN * CAP * 4);   // 12.8 MB
    float* z     = (float*)alloc((size_t)BG * 256 * 4);

    hipMemsetAsync(z, 0, (size_t)BG * 256 * 4, stream);

    const int EB = (EE + 255) / 256;

    // ================= layer 1 =================
    hipMemsetAsync(deg, 0, (size_t)NN * 4, stream);
    fill_first_kernel<<<EB, 256, 0, stream>>>(ei, deg, colb, EE);
    gather_agg_kernel<<<(NN * 64 + 255) / 256, 256, 0, stream>>>(deg, colb, x, mean, NN);
    sage_gemm_kernel<<<(NN + 63) / 64, 256, 0, stream>>>(mean, x, Wl1, Wr1, bl1, hout, NN);
    score_kernel<<<(NN * 64 + 255) / 256, 256, 0, stream>>>(hout, pw1, sc, NN);
    hipMemsetAsync(mapg, 0xFF, (size_t)NN * 4, stream);
    topk_kernel<<<BG, 256, 0, stream>>>(sc, NPG, K1, 512, perm, topv, mapg);
    gather_kernel<<<(BG * K1 * FD + 255) / 256, 256, 0, stream>>>(hout, perm, topv, xp, BG * K1);
    readout_kernel<<<BG, 128, 0, stream>>>(xp, K1, z);

    // ================= layer 2 =================
    const int N2 = BG * K1;   // 25000
    hipMemsetAsync(deg, 0, (size_t)N2 * 4, stream);
    remap_fill_first_kernel<<<EB, 256, 0, stream>>>(ei, mapg, srcb, dstb, emb, deg, colb, EE);
    gather_agg_kernel<<<(N2 * 64 + 255) / 256, 256, 0, stream>>>(deg, colb, xp, mean, N2);
    sage_gemm_kernel<<<(N2 + 63) / 64, 256, 0, stream>>>(mean, xp, Wl2, Wr2, bl2, hout, N2);
    score_kernel<<<(N2 * 64 + 255) / 256, 256, 0, stream>>>(hout, pw2, sc, N2);
    hipMemsetAsync(mapg, 0xFF, (size_t)N2 * 4, stream);
    topk_kernel<<<BG, 256, 0, stream>>>(sc, K1, K2, 256, perm, topv, mapg);
    gather_kernel<<<(BG * K2 * FD + 255) / 256, 256, 0, stream>>>(hout, perm, topv, xp, BG * K2);
    readout_kernel<<<BG, 128, 0, stream>>>(xp, K2, z);

    // ================= layer 3 =================
    const int N3 = BG * K2;   // 12500
    hipMemsetAsync(deg, 0, (size_t)N3 * 4, stream);
    remap_fill_kernel<<<EB, 256, 0, stream>>>(srcb, dstb, emb, mapg, deg, colb, EE);
    gather_agg_kernel<<<(N3 * 64 + 255) / 256, 256, 0, stream>>>(deg, colb, xp, mean, N3);
    sage_gemm_kernel<<<(N3 + 63) / 64, 256, 0, stream>>>(mean, xp, Wl3, Wr3, bl3, hout, N3);
    score_kernel<<<(N3 * 64 + 255) / 256, 256, 0, stream>>>(hout, pw3, sc, N3);
    hipMemsetAsync(mapg, 0xFF, (size_t)N3 * 4, stream);
    topk_kernel<<<BG, 256, 0, stream>>>(sc, K2, K3, 128, perm, topv, mapg);
    gather_kernel<<<(BG * K3 * FD + 255) / 256, 256, 0, stream>>>(hout, perm, topv, xp, BG * K3);
    readout_kernel<<<BG, 128, 0, stream>>>(xp, K3, z);

    // ================= head =================
    head_kernel<<<BG, 256, 0, stream>>>(z, W1, b1, W2, b2, W3, b3, out);
}

// Round 4
// 491.591 us; speedup vs baseline: 3.7807x; 1.1077x over previous
//
#include <hip/hip_runtime.h>
#include <math.h>

// Problem constants (from reference)
#define BG    100        // graphs
#define NPG   500        // nodes per graph (layer 1)
#define FD    128        // feature dim (F_IN == H == 128)
#define EE    600000     // edges
#define NN    50000      // total nodes layer 1
#define K1    250
#define K2    125
#define K3    63
#define CAP   64         // max in-degree capacity (in-deg ~ Poisson(12); P(>64) ~ 1e-30)

// ---------------- slot-CSR build: one edge pass, no scan ----------------
__global__ void fill_first_kernel(const int* __restrict__ ei, int* __restrict__ deg,
                                  int* __restrict__ col, int E) {
    int e = blockIdx.x * blockDim.x + threadIdx.x;
    if (e >= E) return;
    int d = ei[E + e];
    int pos = atomicAdd(&deg[d], 1);
    if (pos < CAP) col[d * CAP + pos] = ei[e];
}

// remap original edges through layer-1 pooling, store remapped edges for layer 3,
// and fill layer-2 neighbor slots — all in one pass
__global__ void remap_fill_first_kernel(const int* __restrict__ ei, const int* __restrict__ mapping,
                                        int* __restrict__ src, int* __restrict__ dst,
                                        float* __restrict__ em, int* __restrict__ deg,
                                        int* __restrict__ col, int E) {
    int e = blockIdx.x * blockDim.x + threadIdx.x;
    if (e >= E) return;
    int ns = mapping[ei[e]], nd = mapping[ei[E + e]];
    bool keep = (ns >= 0) && (nd >= 0);
    em[e]  = keep ? 1.0f : 0.0f;
    src[e] = keep ? ns : 0;
    dst[e] = keep ? nd : 0;
    if (keep) {
        int pos = atomicAdd(&deg[nd], 1);
        if (pos < CAP) col[nd * CAP + pos] = ns;
    }
}

// remap layer-2 edges through layer-2 pooling and fill layer-3 slots
__global__ void remap_fill_kernel(const int* __restrict__ src, const int* __restrict__ dst,
                                  const float* __restrict__ em, const int* __restrict__ mapping,
                                  int* __restrict__ deg, int* __restrict__ col, int E) {
    int e = blockIdx.x * blockDim.x + threadIdx.x;
    if (e >= E) return;
    if (em[e] == 0.0f) return;
    int ns = mapping[src[e]], nd = mapping[dst[e]];
    if (ns >= 0 && nd >= 0) {
        int pos = atomicAdd(&deg[nd], 1);
        if (pos < CAP) col[nd * CAP + pos] = ns;
    }
}

// ---------------- gather-aggregate: mean of neighbor rows ----------------
// float4 per lane: 32 lanes per node, 2 nodes per wave.
__global__ void gather_agg_kernel(const int* __restrict__ deg, const int* __restrict__ col,
                                  const float* __restrict__ x, float* __restrict__ mean, int n) {
    int g = blockIdx.x * blockDim.x + threadIdx.x;
    int node = g >> 5, sub = g & 31;
    if (node >= n) return;
    int d = deg[node]; if (d > CAP) d = CAP;
    const int* cp = col + node * CAP;
    float ax = 0.0f, ay = 0.0f, az = 0.0f, aw = 0.0f;
    for (int j = 0; j < d; ++j) {
        int s = cp[j];
        float4 v = ((const float4*)(x + (long long)s * FD))[sub];
        ax += v.x; ay += v.y; az += v.z; aw += v.w;
    }
    float inv = 1.0f / fmaxf((float)d, 1.0f);
    float4 o; o.x = ax * inv; o.y = ay * inv; o.z = az * inv; o.w = aw * inv;
    ((float4*)(mean + (long long)node * FD))[sub] = o;
}

// ---------------- fused SAGE GEMM + score epilogue ----------------
// h = relu(mean@Wl + x@Wr + bl); score = tanh(h.pw / ||pw||)
// Tile: 64 rows x 128 cols, K=256 logical (mean | x), k-tile 32.
// Thread micro-tile: 4 rows (tr*4..) x 8 cols {4tc..4tc+3, 64+4tc..64+4tc+3}.
__global__ __launch_bounds__(256) void sage_gemm_kernel(
        const float* __restrict__ mean, const float* __restrict__ x,
        const float* __restrict__ Wl, const float* __restrict__ Wr,
        const float* __restrict__ bl, const float* __restrict__ pw,
        float* __restrict__ hout, float* __restrict__ score, int M) {
    __shared__ float As[32 * 68];    // [kk][row], stride 68 (16B-aligned, conflict-reduced)
    __shared__ float Ws[32 * 128];   // [kk][col]
    __shared__ float spart[64 * 16]; // per-row score partials
    __shared__ float snrmp[16];      // ||pw||^2 partials
    int tid  = threadIdx.x;
    int row0 = blockIdx.x * 64;
    int tr   = tid >> 4;             // 0..15
    int tc   = tid & 15;             // 0..15
    float acc[4][8];
#pragma unroll
    for (int r = 0; r < 4; r++)
#pragma unroll
        for (int c = 0; c < 8; c++) acc[r][c] = 0.0f;

    int lrow = tid >> 3;             // 0..31
    int lk   = (tid & 7) * 4;        // 0,4,..,28

    for (int kt = 0; kt < 8; ++kt) {
        bool isMean = kt < 4;
        int kcol = (isMean ? kt * 32 : (kt - 4) * 32) + lk;
        const float* Ab = isMean ? mean : x;
#pragma unroll
        for (int p = 0; p < 2; ++p) {
            int row  = p * 32 + lrow;
            int grow = row0 + row; if (grow > M - 1) grow = M - 1;
            float4 v = *(const float4*)(Ab + (long long)grow * FD + kcol);
            As[(lk + 0) * 68 + row] = v.x;
            As[(lk + 1) * 68 + row] = v.y;
            As[(lk + 2) * 68 + row] = v.z;
            As[(lk + 3) * 68 + row] = v.w;
        }
        {
            int wc  = (tid & 31) * 4;
            int wk0 = tid >> 5;
            const float* WB = isMean ? Wl : Wr;
            int krow0 = isMean ? kt * 32 : (kt - 4) * 32;
#pragma unroll
            for (int q = 0; q < 4; ++q) {
                int kk = wk0 + q * 8;
                float4 v = *(const float4*)(WB + (long long)(krow0 + kk) * FD + wc);
                *(float4*)&Ws[kk * 128 + wc] = v;
            }
        }
        __syncthreads();
#pragma unroll
        for (int kk = 0; kk < 32; ++kk) {
            float4 a  = *(const float4*)&As[kk * 68 + tr * 4];
            float4 b0 = *(const float4*)&Ws[kk * 128 + tc * 4];
            float4 b1 = *(const float4*)&Ws[kk * 128 + 64 + tc * 4];
            float av[4] = {a.x, a.y, a.z, a.w};
            float bv[8] = {b0.x, b0.y, b0.z, b0.w, b1.x, b1.y, b1.z, b1.w};
#pragma unroll
            for (int r = 0; r < 4; r++)
#pragma unroll
                for (int c = 0; c < 8; c++) acc[r][c] += av[r] * bv[c];
        }
        __syncthreads();
    }

    // epilogue: bias + relu + store h, accumulate score partials
    float4 bb0 = *(const float4*)(bl + tc * 4);
    float4 bb1 = *(const float4*)(bl + 64 + tc * 4);
    float4 w0  = *(const float4*)(pw + tc * 4);
    float4 w1  = *(const float4*)(pw + 64 + tc * 4);
    float bvec[8] = {bb0.x, bb0.y, bb0.z, bb0.w, bb1.x, bb1.y, bb1.z, bb1.w};
    float wvec[8] = {w0.x, w0.y, w0.z, w0.w, w1.x, w1.y, w1.z, w1.w};
    if (tr == 0) snrmp[tc] = w0.x*w0.x + w0.y*w0.y + w0.z*w0.z + w0.w*w0.w +
                             w1.x*w1.x + w1.y*w1.y + w1.z*w1.z + w1.w*w1.w;
#pragma unroll
    for (int r = 0; r < 4; r++) {
        int row  = tr * 4 + r;
        int grow = row0 + row;
        float h[8];
        float part = 0.0f;
#pragma unroll
        for (int c = 0; c < 8; c++) {
            h[c] = fmaxf(acc[r][c] + bvec[c], 0.0f);
            part += h[c] * wvec[c];
        }
        spart[row * 16 + tc] = part;
        if (grow < M) {
            float* dstp = hout + (long long)grow * FD;
            *(float4*)(dstp + tc * 4)      = make_float4(h[0], h[1], h[2], h[3]);
            *(float4*)(dstp + 64 + tc * 4) = make_float4(h[4], h[5], h[6], h[7]);
        }
    }
    __syncthreads();
    if (tid < 64) {
        int grow = row0 + tid;
        if (grow < M) {
            float dot = 0.0f;
#pragma unroll
            for (int i = 0; i < 16; i++) dot += spart[tid * 16 + i];
            float nr = 0.0f;
#pragma unroll
            for (int i = 0; i < 16; i++) nr += snrmp[i];
            score[grow] = tanhf(dot / sqrtf(nr));
        }
    }
}

// ---------------- per-graph top-k (bitonic sort in LDS, jax.lax.top_k order) ----------------
__global__ __launch_bounds__(256) void topk_kernel(const float* __restrict__ score,
        int n_per, int k, int SN, int* __restrict__ perm, float* __restrict__ topv,
        int* __restrict__ mapping) {
    __shared__ float skey[512];
    __shared__ int   sidx[512];
    int b = blockIdx.x, tid = threadIdx.x;
    for (int i = tid; i < SN; i += 256) {
        if (i < n_per) { skey[i] = score[b * n_per + i]; sidx[i] = i; }
        else           { skey[i] = -INFINITY;            sidx[i] = 0x7fffffff; }
    }
    __syncthreads();
    for (int ks = 2; ks <= SN; ks <<= 1) {
        for (int j = ks >> 1; j > 0; j >>= 1) {
            for (int i = tid; i < SN; i += 256) {
                int l = i ^ j;
                if (l > i) {
                    float ki = skey[i], kl = skey[l];
                    int   ii = sidx[i], il = sidx[l];
                    bool before = (ki > kl) || (ki == kl && ii < il);
                    bool up = ((i & ks) == 0);
                    if (up ? !before : before) {
                        skey[i] = kl; skey[l] = ki;
                        sidx[i] = il; sidx[l] = ii;
                    }
                }
            }
            __syncthreads();
        }
    }
    for (int i = tid; i < k; i += 256) {
        int old  = sidx[i];
        int oldg = b * n_per + old;
        int newg = b * k + i;
        perm[newg] = oldg;
        topv[newg] = skey[i];
        mapping[oldg] = newg;
    }
}

// ---------------- gather + scale: x_new = h[perm] * topv ----------------
__global__ void gather_kernel(const float* __restrict__ h, const int* __restrict__ perm,
                              const float* __restrict__ topv, float* __restrict__ xn, int rows) {
    int idx = blockIdx.x * blockDim.x + threadIdx.x;
    if (idx >= rows * FD) return;
    int r = idx >> 7;
    xn[idx] = h[(long long)perm[r] * FD + (idx & 127)] * topv[r];
}

// ---------------- readout: z[b] += [max || mean] over k nodes ----------------
__global__ void readout_kernel(const float* __restrict__ xk, int k, float* __restrict__ z) {
    int b = blockIdx.x, c = threadIdx.x;   // 128 threads
    const float* p = xk + (long long)b * k * FD + c;
    float mx = -INFINITY, sm = 0.0f;
    for (int i = 0; i < k; ++i) {
        float v = p[(long long)i * FD];
        mx = fmaxf(mx, v);
        sm += v;
    }
    z[b * 256 + c]       += mx;
    z[b * 256 + 128 + c] += sm / (float)k;
}

// ---------------- MLP head + log_softmax, one block per graph ----------------
__global__ __launch_bounds__(256) void head_kernel(const float* __restrict__ z,
        const float* __restrict__ W1, const float* __restrict__ b1,
        const float* __restrict__ W2, const float* __restrict__ b2,
        const float* __restrict__ W3, const float* __restrict__ b3,
        float* __restrict__ out) {
    __shared__ float zs[256], t1[128], t2[64], t3[16];
    int b = blockIdx.x, t = threadIdx.x;
    zs[t] = z[b * 256 + t];
    __syncthreads();
    if (t < 128) {
        float a = b1[t];
        for (int k = 0; k < 256; k++) a += zs[k] * W1[k * 128 + t];
        t1[t] = fmaxf(a, 0.0f);
    }
    __syncthreads();
    if (t < 64) {
        float a = b2[t];
        for (int k = 0; k < 128; k++) a += t1[k] * W2[k * 64 + t];
        t2[t] = fmaxf(a, 0.0f);
    }
    __syncthreads();
    if (t < 10) {
        float a = b3[t];
        for (int k = 0; k < 64; k++) a += t2[k] * W3[k * 10 + t];
        t3[t] = a;
    }
    __syncthreads();
    if (t == 0) {
        float m = -INFINITY;
        for (int i = 0; i < 10; i++) m = fmaxf(m, t3[i]);
        float s = 0.0f;
        for (int i = 0; i < 10; i++) s += expf(t3[i] - m);
        float ls = logf(s);
        for (int i = 0; i < 10; i++) out[b * 10 + i] = t3[i] - m - ls;
    }
}

extern "C" void kernel_launch(void* const* d_in, const int* in_sizes, int n_in,
                              void* d_out, int out_size, void* d_ws, size_t ws_size,
                              hipStream_t stream) {
    (void)in_sizes; (void)n_in; (void)out_size; (void)ws_size;
    const float* x   = (const float*)d_in[0];
    const int*   ei  = (const int*)d_in[1];
    const float* Wl1 = (const float*)d_in[2];
    const float* bl1 = (const float*)d_in[3];
    const float* Wr1 = (const float*)d_in[4];
    const float* Wl2 = (const float*)d_in[5];
    const float* bl2 = (const float*)d_in[6];
    const float* Wr2 = (const float*)d_in[7];
    const float* Wl3 = (const float*)d_in[8];
    const float* bl3 = (const float*)d_in[9];
    const float* Wr3 = (const float*)d_in[10];
    const float* pw1 = (const float*)d_in[11];
    const float* pw2 = (const float*)d_in[12];
    const float* pw3 = (const float*)d_in[13];
    const float* W1  = (const float*)d_in[14];
    const float* b1  = (const float*)d_in[15];
    const float* W2  = (const float*)d_in[16];
    const float* b2  = (const float*)d_in[17];
    const float* W3  = (const float*)d_in[18];
    const float* b3  = (const float*)d_in[19];
    float* out = (float*)d_out;

    // workspace layout
    char* ws = (char*)d_ws;
    size_t off = 0;
    auto alloc = [&](size_t bytes) {
        char* p = ws + off;
        off = (off + bytes + 255) & ~(size_t)255;
        return p;
    };
    float* mean  = (float*)alloc((size_t)NN * FD * 4);
    float* hout  = (float*)alloc((size_t)NN * FD * 4);
    float* xp    = (float*)alloc((size_t)BG * K1 * FD * 4);
    float* sc    = (float*)alloc((size_t)NN * 4);
    int*   mapg  = (int*)  alloc((size_t)NN * 4);
    int*   perm  = (int*)  alloc((size_t)BG * K1 * 4);
    float* topv  = (float*)alloc((size_t)BG * K1 * 4);
    int*   srcb  = (int*)  alloc((size_t)EE * 4);
    int*   dstb  = (int*)  alloc((size_t)EE * 4);
    float* emb   = (float*)alloc((size_t)EE * 4);
    int*   deg   = (int*)  alloc((size_t)NN * 4);
    int*   colb  = (int*)  alloc((size_t)NN * CAP * 4);   // 12.8 MB
    float* z     = (float*)alloc((size_t)BG * 256 * 4);

    hipMemsetAsync(z, 0, (size_t)BG * 256 * 4, stream);

    const int EB = (EE + 255) / 256;

    // ================= layer 1 =================
    hipMemsetAsync(deg, 0, (size_t)NN * 4, stream);
    fill_first_kernel<<<EB, 256, 0, stream>>>(ei, deg, colb, EE);
    gather_agg_kernel<<<(NN * 32 + 255) / 256, 256, 0, stream>>>(deg, colb, x, mean, NN);
    sage_gemm_kernel<<<(NN + 63) / 64, 256, 0, stream>>>(mean, x, Wl1, Wr1, bl1, pw1, hout, sc, NN);
    hipMemsetAsync(mapg, 0xFF, (size_t)NN * 4, stream);
    topk_kernel<<<BG, 256, 0, stream>>>(sc, NPG, K1, 512, perm, topv, mapg);
    gather_kernel<<<(BG * K1 * FD + 255) / 256, 256, 0, stream>>>(hout, perm, topv, xp, BG * K1);
    readout_kernel<<<BG, 128, 0, stream>>>(xp, K1, z);

    // ================= layer 2 =================
    const int N2 = BG * K1;   // 25000
    hipMemsetAsync(deg, 0, (size_t)N2 * 4, stream);
    remap_fill_first_kernel<<<EB, 256, 0, stream>>>(ei, mapg, srcb, dstb, emb, deg, colb, EE);
    gather_agg_kernel<<<(N2 * 32 + 255) / 256, 256, 0, stream>>>(deg, colb, xp, mean, N2);
    sage_gemm_kernel<<<(N2 + 63) / 64, 256, 0, stream>>>(mean, xp, Wl2, Wr2, bl2, pw2, hout, sc, N2);
    hipMemsetAsync(mapg, 0xFF, (size_t)N2 * 4, stream);
    topk_kernel<<<BG, 256, 0, stream>>>(sc, K1, K2, 256, perm, topv, mapg);
    gather_kernel<<<(BG * K2 * FD + 255) / 256, 256, 0, stream>>>(hout, perm, topv, xp, BG * K2);
    readout_kernel<<<BG, 128, 0, stream>>>(xp, K2, z);

    // ================= layer 3 =================
    const int N3 = BG * K2;   // 12500
    hipMemsetAsync(deg, 0, (size_t)N3 * 4, stream);
    remap_fill_kernel<<<EB, 256, 0, stream>>>(srcb, dstb, emb, mapg, deg, colb, EE);
    gather_agg_kernel<<<(N3 * 32 + 255) / 256, 256, 0, stream>>>(deg, colb, xp, mean, N3);
    sage_gemm_kernel<<<(N3 + 63) / 64, 256, 0, stream>>>(mean, xp, Wl3, Wr3, bl3, pw3, hout, sc, N3);
    hipMemsetAsync(mapg, 0xFF, (size_t)N3 * 4, stream);
    topk_kernel<<<BG, 256, 0, stream>>>(sc, K2, K3, 128, perm, topv, mapg);
    gather_kernel<<<(BG * K3 * FD + 255) / 256, 256, 0, stream>>>(hout, perm, topv, xp, BG * K3);
    readout_kernel<<<BG, 128, 0, stream>>>(xp, K3, z);

    // ================= head =================
    head_kernel<<<BG, 256, 0, stream>>>(z, W1, b1, W2, b2, W3, b3, out);
}

// Round 5
// 374.350 us; speedup vs baseline: 4.9648x; 1.3132x over previous
//
#include <hip/hip_runtime.h>
#include <math.h>

// Problem constants (from reference)
#define BG    100        // graphs
#define NPG   500        // nodes per graph (layer 1)
#define FD    128        // feature dim (F_IN == H == 128)
#define EE    600000     // edges
#define NN    50000      // total nodes layer 1
#define K1    250
#define K2    125
#define K3    63
#define CAP   64         // max in-degree capacity (in-deg ~ Poisson(12); P(>64) ~ 1e-30)

// ---------------- slot-CSR build: one edge pass, no scan ----------------
__global__ void fill_first_kernel(const int* __restrict__ ei, int* __restrict__ deg,
                                  int* __restrict__ col, int E) {
    int e = blockIdx.x * blockDim.x + threadIdx.x;
    if (e >= E) return;
    int d = ei[E + e];
    int pos = atomicAdd(&deg[d], 1);
    if (pos < CAP) col[d * CAP + pos] = ei[e];
}

// remap original edges through layer-1 pooling, store remapped edges for layer 3,
// and fill layer-2 neighbor slots — all in one pass
__global__ void remap_fill_first_kernel(const int* __restrict__ ei, const int* __restrict__ mapping,
                                        int* __restrict__ src, int* __restrict__ dst,
                                        float* __restrict__ em, int* __restrict__ deg,
                                        int* __restrict__ col, int E) {
    int e = blockIdx.x * blockDim.x + threadIdx.x;
    if (e >= E) return;
    int ns = mapping[ei[e]], nd = mapping[ei[E + e]];
    bool keep = (ns >= 0) && (nd >= 0);
    em[e]  = keep ? 1.0f : 0.0f;
    src[e] = keep ? ns : 0;
    dst[e] = keep ? nd : 0;
    if (keep) {
        int pos = atomicAdd(&deg[nd], 1);
        if (pos < CAP) col[nd * CAP + pos] = ns;
    }
}

// remap layer-2 edges through layer-2 pooling and fill layer-3 slots
__global__ void remap_fill_kernel(const int* __restrict__ src, const int* __restrict__ dst,
                                  const float* __restrict__ em, const int* __restrict__ mapping,
                                  int* __restrict__ deg, int* __restrict__ col, int E) {
    int e = blockIdx.x * blockDim.x + threadIdx.x;
    if (e >= E) return;
    if (em[e] == 0.0f) return;
    int ns = mapping[src[e]], nd = mapping[dst[e]];
    if (ns >= 0 && nd >= 0) {
        int pos = atomicAdd(&deg[nd], 1);
        if (pos < CAP) col[nd * CAP + pos] = ns;
    }
}

// ---------------- gather-aggregate: mean of neighbor rows ----------------
// float4 per lane: 32 lanes per node, 2 nodes per wave.
__global__ void gather_agg_kernel(const int* __restrict__ deg, const int* __restrict__ col,
                                  const float* __restrict__ x, float* __restrict__ mean, int n) {
    int g = blockIdx.x * blockDim.x + threadIdx.x;
    int node = g >> 5, sub = g & 31;
    if (node >= n) return;
    int d = deg[node]; if (d > CAP) d = CAP;
    const int* cp = col + node * CAP;
    float ax = 0.0f, ay = 0.0f, az = 0.0f, aw = 0.0f;
    for (int j = 0; j < d; ++j) {
        int s = cp[j];
        float4 v = ((const float4*)(x + (long long)s * FD))[sub];
        ax += v.x; ay += v.y; az += v.z; aw += v.w;
    }
    float inv = 1.0f / fmaxf((float)d, 1.0f);
    float4 o; o.x = ax * inv; o.y = ay * inv; o.z = az * inv; o.w = aw * inv;
    ((float4*)(mean + (long long)node * FD))[sub] = o;
}

// ---------------- fused SAGE GEMM + score epilogue ----------------
// h = relu(mean@Wl + x@Wr + bl); score = tanh(h.pw / ||pw||)
__global__ __launch_bounds__(256) void sage_gemm_kernel(
        const float* __restrict__ mean, const float* __restrict__ x,
        const float* __restrict__ Wl, const float* __restrict__ Wr,
        const float* __restrict__ bl, const float* __restrict__ pw,
        float* __restrict__ hout, float* __restrict__ score, int M) {
    __shared__ float As[32 * 68];    // [kk][row], stride 68
    __shared__ float Ws[32 * 128];   // [kk][col]
    __shared__ float spart[64 * 16]; // per-row score partials
    __shared__ float snrmp[16];      // ||pw||^2 partials
    int tid  = threadIdx.x;
    int row0 = blockIdx.x * 64;
    int tr   = tid >> 4;             // 0..15
    int tc   = tid & 15;             // 0..15
    float acc[4][8];
#pragma unroll
    for (int r = 0; r < 4; r++)
#pragma unroll
        for (int c = 0; c < 8; c++) acc[r][c] = 0.0f;

    int lrow = tid >> 3;             // 0..31
    int lk   = (tid & 7) * 4;        // 0,4,..,28

    for (int kt = 0; kt < 8; ++kt) {
        bool isMean = kt < 4;
        int kcol = (isMean ? kt * 32 : (kt - 4) * 32) + lk;
        const float* Ab = isMean ? mean : x;
#pragma unroll
        for (int p = 0; p < 2; ++p) {
            int row  = p * 32 + lrow;
            int grow = row0 + row; if (grow > M - 1) grow = M - 1;
            float4 v = *(const float4*)(Ab + (long long)grow * FD + kcol);
            As[(lk + 0) * 68 + row] = v.x;
            As[(lk + 1) * 68 + row] = v.y;
            As[(lk + 2) * 68 + row] = v.z;
            As[(lk + 3) * 68 + row] = v.w;
        }
        {
            int wc  = (tid & 31) * 4;
            int wk0 = tid >> 5;
            const float* WB = isMean ? Wl : Wr;
            int krow0 = isMean ? kt * 32 : (kt - 4) * 32;
#pragma unroll
            for (int q = 0; q < 4; ++q) {
                int kk = wk0 + q * 8;
                float4 v = *(const float4*)(WB + (long long)(krow0 + kk) * FD + wc);
                *(float4*)&Ws[kk * 128 + wc] = v;
            }
        }
        __syncthreads();
#pragma unroll
        for (int kk = 0; kk < 32; ++kk) {
            float4 a  = *(const float4*)&As[kk * 68 + tr * 4];
            float4 b0 = *(const float4*)&Ws[kk * 128 + tc * 4];
            float4 b1 = *(const float4*)&Ws[kk * 128 + 64 + tc * 4];
            float av[4] = {a.x, a.y, a.z, a.w};
            float bv[8] = {b0.x, b0.y, b0.z, b0.w, b1.x, b1.y, b1.z, b1.w};
#pragma unroll
            for (int r = 0; r < 4; r++)
#pragma unroll
                for (int c = 0; c < 8; c++) acc[r][c] += av[r] * bv[c];
        }
        __syncthreads();
    }

    float4 bb0 = *(const float4*)(bl + tc * 4);
    float4 bb1 = *(const float4*)(bl + 64 + tc * 4);
    float4 w0  = *(const float4*)(pw + tc * 4);
    float4 w1  = *(const float4*)(pw + 64 + tc * 4);
    float bvec[8] = {bb0.x, bb0.y, bb0.z, bb0.w, bb1.x, bb1.y, bb1.z, bb1.w};
    float wvec[8] = {w0.x, w0.y, w0.z, w0.w, w1.x, w1.y, w1.z, w1.w};
    if (tr == 0) snrmp[tc] = w0.x*w0.x + w0.y*w0.y + w0.z*w0.z + w0.w*w0.w +
                             w1.x*w1.x + w1.y*w1.y + w1.z*w1.z + w1.w*w1.w;
#pragma unroll
    for (int r = 0; r < 4; r++) {
        int row  = tr * 4 + r;
        int grow = row0 + row;
        float h[8];
        float part = 0.0f;
#pragma unroll
        for (int c = 0; c < 8; c++) {
            h[c] = fmaxf(acc[r][c] + bvec[c], 0.0f);
            part += h[c] * wvec[c];
        }
        spart[row * 16 + tc] = part;
        if (grow < M) {
            float* dstp = hout + (long long)grow * FD;
            *(float4*)(dstp + tc * 4)      = make_float4(h[0], h[1], h[2], h[3]);
            *(float4*)(dstp + 64 + tc * 4) = make_float4(h[4], h[5], h[6], h[7]);
        }
    }
    __syncthreads();
    if (tid < 64) {
        int grow = row0 + tid;
        if (grow < M) {
            float dot = 0.0f;
#pragma unroll
            for (int i = 0; i < 16; i++) dot += spart[tid * 16 + i];
            float nr = 0.0f;
#pragma unroll
            for (int i = 0; i < 16; i++) nr += snrmp[i];
            score[grow] = tanhf(dot / sqrtf(nr));
        }
    }
}

// ---------------- fused per-graph tail: top-k sort + mapping + gather*score +
// readout (+ optional MLP head on the last layer) ----------------
// One block per graph, 1024 threads. mode: 0 = z=, 1 = z+=, 2 = z-final + head.
__global__ __launch_bounds__(1024) void topk_gather_readout_kernel(
        const float* __restrict__ score, const float* __restrict__ hout,
        int n_per, int k, int SN,
        float* __restrict__ xp, int* __restrict__ mapping,
        int* __restrict__ next_deg,
        float* __restrict__ z, int mode,
        const float* __restrict__ W1, const float* __restrict__ b1,
        const float* __restrict__ W2, const float* __restrict__ b2,
        const float* __restrict__ W3, const float* __restrict__ b3,
        float* __restrict__ out) {
    __shared__ float skey[512];
    __shared__ int   sidx[512];
    __shared__ float pmax[1024];
    __shared__ float psum[1024];
    __shared__ float zs[256], t1[128], t2[64], t3[16];
    int b = blockIdx.x, tid = threadIdx.x;

    // load scores + pad; init mapping slice to -1; zero next layer's deg slice
    for (int i = tid; i < SN; i += 1024) {
        if (i < n_per) { skey[i] = score[b * n_per + i]; sidx[i] = i; }
        else           { skey[i] = -INFINITY;            sidx[i] = 0x7fffffff; }
    }
    for (int i = tid; i < n_per; i += 1024) mapping[b * n_per + i] = -1;
    if (next_deg) for (int i = tid; i < k; i += 1024) next_deg[b * k + i] = 0;
    __syncthreads();

    // bitonic sort: desc value, tie -> asc index (jax.lax.top_k order)
    for (int ks = 2; ks <= SN; ks <<= 1) {
        for (int j = ks >> 1; j > 0; j >>= 1) {
            for (int i = tid; i < SN; i += 1024) {
                int l = i ^ j;
                if (l > i) {
                    float ki = skey[i], kl = skey[l];
                    int   ii = sidx[i], il = sidx[l];
                    bool before = (ki > kl) || (ki == kl && ii < il);
                    bool up = ((i & ks) == 0);
                    if (up ? !before : before) {
                        skey[i] = kl; skey[l] = ki;
                        sidx[i] = il; sidx[l] = ii;
                    }
                }
            }
            __syncthreads();
        }
    }

    // mapping for kept nodes
    for (int i = tid; i < k; i += 1024) mapping[b * n_per + sidx[i]] = b * k + i;

    // gather + scale + readout partials: c = channel, s = row slice (8 slices)
    int c = tid & 127, s = tid >> 7;
    float mx = -INFINITY, sm = 0.0f;
    for (int r = s; r < k; r += 8) {
        long long g = (long long)(b * n_per + sidx[r]) * FD + c;
        float v = hout[g] * skey[r];
        xp[(long long)(b * k + r) * FD + c] = v;
        mx = fmaxf(mx, v); sm += v;
    }
    pmax[tid] = mx; psum[tid] = sm;
    __syncthreads();
    if (tid < 128) {
        float m = -INFINITY, su = 0.0f;
#pragma unroll
        for (int i = 0; i < 8; i++) {
            m = fmaxf(m, pmax[i * 128 + tid]);
            su += psum[i * 128 + tid];
        }
        float mean = su / (float)k;
        if (mode == 0)      { z[b * 256 + tid] = m;  z[b * 256 + 128 + tid] = mean;  }
        else if (mode == 1) { z[b * 256 + tid] += m; z[b * 256 + 128 + tid] += mean; }
        else {
            zs[tid]       = z[b * 256 + tid] + m;
            zs[128 + tid] = z[b * 256 + 128 + tid] + mean;
        }
    }
    if (mode == 2) {
        __syncthreads();
        if (tid < 128) {
            float a = b1[tid];
            for (int kk = 0; kk < 256; kk++) a += zs[kk] * W1[kk * 128 + tid];
            t1[tid] = fmaxf(a, 0.0f);
        }
        __syncthreads();
        if (tid < 64) {
            float a = b2[tid];
            for (int kk = 0; kk < 128; kk++) a += t1[kk] * W2[kk * 64 + tid];
            t2[tid] = fmaxf(a, 0.0f);
        }
        __syncthreads();
        if (tid < 10) {
            float a = b3[tid];
            for (int kk = 0; kk < 64; kk++) a += t2[kk] * W3[kk * 10 + tid];
            t3[tid] = a;
        }
        __syncthreads();
        if (tid == 0) {
            float m = -INFINITY;
            for (int i = 0; i < 10; i++) m = fmaxf(m, t3[i]);
            float su = 0.0f;
            for (int i = 0; i < 10; i++) su += expf(t3[i] - m);
            float ls = logf(su);
            for (int i = 0; i < 10; i++) out[b * 10 + i] = t3[i] - m - ls;
        }
    }
}

extern "C" void kernel_launch(void* const* d_in, const int* in_sizes, int n_in,
                              void* d_out, int out_size, void* d_ws, size_t ws_size,
                              hipStream_t stream) {
    (void)in_sizes; (void)n_in; (void)out_size; (void)ws_size;
    const float* x   = (const float*)d_in[0];
    const int*   ei  = (const int*)d_in[1];
    const float* Wl1 = (const float*)d_in[2];
    const float* bl1 = (const float*)d_in[3];
    const float* Wr1 = (const float*)d_in[4];
    const float* Wl2 = (const float*)d_in[5];
    const float* bl2 = (const float*)d_in[6];
    const float* Wr2 = (const float*)d_in[7];
    const float* Wl3 = (const float*)d_in[8];
    const float* bl3 = (const float*)d_in[9];
    const float* Wr3 = (const float*)d_in[10];
    const float* pw1 = (const float*)d_in[11];
    const float* pw2 = (const float*)d_in[12];
    const float* pw3 = (const float*)d_in[13];
    const float* W1  = (const float*)d_in[14];
    const float* b1  = (const float*)d_in[15];
    const float* W2  = (const float*)d_in[16];
    const float* b2  = (const float*)d_in[17];
    const float* W3  = (const float*)d_in[18];
    const float* b3  = (const float*)d_in[19];
    float* out = (float*)d_out;

    // workspace layout
    char* ws = (char*)d_ws;
    size_t off = 0;
    auto alloc = [&](size_t bytes) {
        char* p = ws + off;
        off = (off + bytes + 255) & ~(size_t)255;
        return p;
    };
    float* mean  = (float*)alloc((size_t)NN * FD * 4);
    float* hout  = (float*)alloc((size_t)NN * FD * 4);
    float* xp    = (float*)alloc((size_t)BG * K1 * FD * 4);
    float* sc    = (float*)alloc((size_t)NN * 4);
    int*   mapg  = (int*)  alloc((size_t)NN * 4);
    int*   srcb  = (int*)  alloc((size_t)EE * 4);
    int*   dstb  = (int*)  alloc((size_t)EE * 4);
    float* emb   = (float*)alloc((size_t)EE * 4);
    int*   deg   = (int*)  alloc((size_t)NN * 4);
    int*   colb  = (int*)  alloc((size_t)NN * CAP * 4);   // 12.8 MB
    float* z     = (float*)alloc((size_t)BG * 256 * 4);

    const int EB = (EE + 255) / 256;

    // ================= layer 1 =================
    hipMemsetAsync(deg, 0, (size_t)NN * 4, stream);
    fill_first_kernel<<<EB, 256, 0, stream>>>(ei, deg, colb, EE);
    gather_agg_kernel<<<(NN * 32 + 255) / 256, 256, 0, stream>>>(deg, colb, x, mean, NN);
    sage_gemm_kernel<<<(NN + 63) / 64, 256, 0, stream>>>(mean, x, Wl1, Wr1, bl1, pw1, hout, sc, NN);
    topk_gather_readout_kernel<<<BG, 1024, 0, stream>>>(sc, hout, NPG, K1, 512, xp, mapg, deg,
                                                        z, 0, W1, b1, W2, b2, W3, b3, out);

    // ================= layer 2 =================
    const int N2 = BG * K1;   // 25000
    remap_fill_first_kernel<<<EB, 256, 0, stream>>>(ei, mapg, srcb, dstb, emb, deg, colb, EE);
    gather_agg_kernel<<<(N2 * 32 + 255) / 256, 256, 0, stream>>>(deg, colb, xp, mean, N2);
    sage_gemm_kernel<<<(N2 + 63) / 64, 256, 0, stream>>>(mean, xp, Wl2, Wr2, bl2, pw2, hout, sc, N2);
    topk_gather_readout_kernel<<<BG, 1024, 0, stream>>>(sc, hout, K1, K2, 256, xp, mapg, deg,
                                                        z, 1, W1, b1, W2, b2, W3, b3, out);

    // ================= layer 3 =================
    const int N3 = BG * K2;   // 12500
    remap_fill_kernel<<<EB, 256, 0, stream>>>(srcb, dstb, emb, mapg, deg, colb, EE);
    gather_agg_kernel<<<(N3 * 32 + 255) / 256, 256, 0, stream>>>(deg, colb, xp, mean, N3);
    sage_gemm_kernel<<<(N3 + 63) / 64, 256, 0, stream>>>(mean, xp, Wl3, Wr3, bl3, pw3, hout, sc, N3);
    topk_gather_readout_kernel<<<BG, 1024, 0, stream>>>(sc, hout, K2, K3, 128, xp, mapg, (int*)0,
                                                        z, 2, W1, b1, W2, b2, W3, b3, out);
}